// Round 2
// baseline (240.633 us; speedup 1.0000x reference)
//
#include <hip/hip_runtime.h>

typedef __attribute__((ext_vector_type(8))) _Float16 half8;  // 8 x fp16 (MFMA A/B frag)
typedef __attribute__((ext_vector_type(4))) float f32x4;     // MFMA C/D frag
typedef __attribute__((ext_vector_type(2))) unsigned int uint2v;

#define LOG2E 1.44269504088896340736f

__device__ __forceinline__ unsigned short f2h(float x) {
  _Float16 h = (_Float16)x;  // RNE
  union { _Float16 h; unsigned short u; } v; v.h = h;
  return v.u;
}

// ---------------------------------------------------------------------------
// Kernel 0: pack weights: WT[w][n][k] = fp16(W_w[k][n]),  w in {q,k,v}
// ---------------------------------------------------------------------------
__global__ __launch_bounds__(256) void pack_w(
    const float* __restrict__ Wq, const float* __restrict__ Wk,
    const float* __restrict__ Wv, unsigned short* __restrict__ WT) {
  int idx = blockIdx.x * 256 + threadIdx.x;  // 3*128*256 = 98304 total
  int w = idx >> 15;                         // 32768 per weight
  int r = idx & 32767;
  int n = r >> 8;                            // 0..127 (out feature)
  int k = r & 255;                           // 0..255 (in feature)
  const float* W = (w == 0) ? Wq : ((w == 1) ? Wk : Wv);
  WT[idx] = f2h(W[k * 128 + n]);
}

// ---------------------------------------------------------------------------
// Kernel 1: projections.  X[16384,256] fp32 -> Q,K fp16 [16384,128] row-major,
//           V^T fp16 [128,16384].
// Block: 256 thr (4 waves), M-tile 64 (16 rows/wave), BK=64, full N=128.
// ---------------------------------------------------------------------------
__global__ __launch_bounds__(256) void proj_kernel(
    const float* __restrict__ seq, const unsigned short* __restrict__ WT,
    unsigned short* __restrict__ Qb, unsigned short* __restrict__ Kb,
    unsigned short* __restrict__ VTb) {
  __shared__ unsigned short X_lds[64 * 72];    // 64 rows x 64 fp16 (+8 pad)
  __shared__ unsigned short WT_lds[128 * 72];  // 128 rows x 64 fp16 (+8 pad)

  const int tid = threadIdx.x;
  const int wv = tid >> 6, lane = tid & 63, lo = lane & 15, hi = lane >> 4;
  const int mb = blockIdx.x * 64;

  f32x4 accQ[8], accK[8], accV[8];
  const f32x4 z = {0.f, 0.f, 0.f, 0.f};
#pragma unroll
  for (int e = 0; e < 8; ++e) { accQ[e] = z; accK[e] = z; accV[e] = z; }

  half8 a[2];

  for (int kt = 0; kt < 4; ++kt) {
    __syncthreads();  // prev kt's MFMAs done reading X_lds
    // stage X tile (fp32 -> fp16): 64 rows x 16 float4-chunks
#pragma unroll
    for (int i = tid; i < 1024; i += 256) {
      int row = i >> 4, c = i & 15;
      f32x4 xv = *reinterpret_cast<const f32x4*>(&seq[(mb + row) * 256 + kt * 64 + c * 4]);
      uint2v pk;
      pk[0] = (unsigned)f2h(xv[0]) | ((unsigned)f2h(xv[1]) << 16);
      pk[1] = (unsigned)f2h(xv[2]) | ((unsigned)f2h(xv[3]) << 16);
      *reinterpret_cast<uint2v*>(&X_lds[row * 72 + c * 4]) = pk;
    }
#pragma unroll
    for (int w = 0; w < 3; ++w) {
      __syncthreads();  // X staged (w==0) / prev w done reading WT_lds
      // stage WT(w, kt): 128 rows x 8 chunks of 8 fp16
#pragma unroll
      for (int i = tid; i < 1024; i += 256) {
        int row = i >> 3, c = i & 7;
        *reinterpret_cast<half8*>(&WT_lds[row * 72 + c * 8]) =
            *reinterpret_cast<const half8*>(&WT[(w << 15) + (row << 8) + kt * 64 + c * 8]);
      }
      __syncthreads();
      if (w == 0) {
        a[0] = *reinterpret_cast<const half8*>(&X_lds[(wv * 16 + lo) * 72 + hi * 8]);
        a[1] = *reinterpret_cast<const half8*>(&X_lds[(wv * 16 + lo) * 72 + 32 + hi * 8]);
      }
      if (w < 2) {
        // D[row][out] = X[row][k] * W[k][out];  B-frag from WT rows (n=lo)
#pragma unroll
        for (int e8 = 0; e8 < 8; ++e8) {
#pragma unroll
          for (int kc = 0; kc < 2; ++kc) {
            half8 bw = *reinterpret_cast<const half8*>(
                &WT_lds[(e8 * 16 + lo) * 72 + kc * 32 + hi * 8]);
            if (w == 0)
              accQ[e8] = __builtin_amdgcn_mfma_f32_16x16x32_f16(a[kc], bw, accQ[e8], 0, 0, 0);
            else
              accK[e8] = __builtin_amdgcn_mfma_f32_16x16x32_f16(a[kc], bw, accK[e8], 0, 0, 0);
          }
        }
      } else {
        // V^T: D[out][row] = W^T[out][k] * X^T[k][row]; A from WT rows, B == a[kc]
#pragma unroll
        for (int f8 = 0; f8 < 8; ++f8) {
#pragma unroll
          for (int kc = 0; kc < 2; ++kc) {
            half8 aw = *reinterpret_cast<const half8*>(
                &WT_lds[(f8 * 16 + lo) * 72 + kc * 32 + hi * 8]);
            accV[f8] = __builtin_amdgcn_mfma_f32_16x16x32_f16(aw, a[kc], accV[f8], 0, 0, 0);
          }
        }
      }
    }
  }
  // epilogue: C/D layout col = lane&15, row = (lane>>4)*4 + i
#pragma unroll
  for (int e8 = 0; e8 < 8; ++e8) {
#pragma unroll
    for (int i = 0; i < 4; ++i) {
      int row = mb + wv * 16 + hi * 4 + i;
      int col = e8 * 16 + lo;
      Qb[row * 128 + col] = f2h(accQ[e8][i]);
      Kb[row * 128 + col] = f2h(accK[e8][i]);
      // V^T: rows = out-feature, cols = token
      VTb[(e8 * 16 + hi * 4 + i) * 16384 + mb + wv * 16 + lo] = f2h(accV[e8][i]);
    }
  }
}

// ---------------------------------------------------------------------------
// Kernel 2: flash attention (no scale, no mask).
// Block: 256 thr = 4 waves; QBLK=64 (16 q-rows/wave); KVBLK=64.
// Swapped QK^T: S^T = K*Q^T so each lane owns one q-row (lo).
// ---------------------------------------------------------------------------
__global__ __launch_bounds__(256) void attn_kernel(
    const unsigned short* __restrict__ Qb, const unsigned short* __restrict__ Kb,
    const unsigned short* __restrict__ VTb, float* __restrict__ out) {
  __shared__ unsigned short K_lds[64 * 136];       // 64 kv-rows x 128 feat (+8 pad)
  __shared__ unsigned short VT_lds[128 * 72];      // 128 feat-rows x 64 kv (+8 pad)
  __shared__ unsigned short P_lds[4 * 16 * 72];    // per-wave 16 q x 64 kv (+8 pad)

  const int tid = threadIdx.x;
  const int wv = tid >> 6, lane = tid & 63, lo = lane & 15, hi = lane >> 4;
  // XCD-aware swizzle: blocks with same (blk&7) land on one XCD; give each
  // XCD one batch's K/V (fits 4 MB L2). Bijective [0,256) -> (b,qt).
  const int b = (blockIdx.x & 7) >> 1;
  const int qt = ((blockIdx.x >> 3) << 1) | (blockIdx.x & 1);

  const int qrow = b * 4096 + qt * 64 + wv * 16;
  half8 qf[4];
#pragma unroll
  for (int kc = 0; kc < 4; ++kc)
    qf[kc] = *reinterpret_cast<const half8*>(&Qb[(qrow + lo) * 128 + kc * 32 + hi * 8]);

  f32x4 acc[8];
  const f32x4 z = {0.f, 0.f, 0.f, 0.f};
#pragma unroll
  for (int e = 0; e < 8; ++e) acc[e] = z;
  float m = -INFINITY, l = 0.f;
  unsigned short* Pw = &P_lds[wv * 16 * 72];

  for (int kt = 0; kt < 64; ++kt) {
    __syncthreads();  // prev tile's LDS reads complete
    const int kvbase = b * 4096 + kt * 64;
    // stage K tile: 64 rows x 16 chunks of 8 fp16
#pragma unroll
    for (int i = tid; i < 1024; i += 256) {
      int row = i >> 4, c = i & 15;
      *reinterpret_cast<half8*>(&K_lds[row * 136 + c * 8]) =
          *reinterpret_cast<const half8*>(&Kb[(kvbase + row) * 128 + c * 8]);
    }
    // stage V^T tile: 128 rows x 8 chunks of 8 fp16
#pragma unroll
    for (int i = tid; i < 1024; i += 256) {
      int row = i >> 3, c = i & 7;
      *reinterpret_cast<half8*>(&VT_lds[row * 72 + c * 8]) =
          *reinterpret_cast<const half8*>(&VTb[row * 16384 + kvbase + c * 8]);
    }
    __syncthreads();

    // S^T = K * Q^T : lane holds S[q=lo][kv = f*16 + hi*4 + i]
    f32x4 sf[4];
#pragma unroll
    for (int f = 0; f < 4; ++f) sf[f] = z;
#pragma unroll
    for (int f = 0; f < 4; ++f) {
#pragma unroll
      for (int kc = 0; kc < 4; ++kc) {
        half8 ak = *reinterpret_cast<const half8*>(
            &K_lds[(f * 16 + lo) * 136 + kc * 32 + hi * 8]);
        sf[f] = __builtin_amdgcn_mfma_f32_16x16x32_f16(ak, qf[kc], sf[f], 0, 0, 0);
      }
    }

    // online softmax (per q-row = lo)
    float tmax = -INFINITY;
#pragma unroll
    for (int f = 0; f < 4; ++f)
#pragma unroll
      for (int i = 0; i < 4; ++i) tmax = fmaxf(tmax, sf[f][i]);
    tmax = fmaxf(tmax, __shfl_xor(tmax, 16, 64));
    tmax = fmaxf(tmax, __shfl_xor(tmax, 32, 64));
    float mn = fmaxf(m, tmax);
    float alpha = exp2f((m - mn) * LOG2E);
    float ts = 0.f;
#pragma unroll
    for (int f = 0; f < 4; ++f)
#pragma unroll
      for (int i = 0; i < 4; ++i) {
        float p = exp2f((sf[f][i] - mn) * LOG2E);
        sf[f][i] = p;
        ts += p;
      }
    ts += __shfl_xor(ts, 16, 64);
    ts += __shfl_xor(ts, 32, 64);
    l = l * alpha + ts;
    m = mn;

    // write P (fp16) to per-wave LDS in A-frag-readable layout
#pragma unroll
    for (int f = 0; f < 4; ++f) {
      uint2v pk;
      pk[0] = (unsigned)f2h(sf[f][0]) | ((unsigned)f2h(sf[f][1]) << 16);
      pk[1] = (unsigned)f2h(sf[f][2]) | ((unsigned)f2h(sf[f][3]) << 16);
      *reinterpret_cast<uint2v*>(&Pw[lo * 72 + f * 16 + hi * 4]) = pk;
    }
    // rescale accumulator (acc rows are q = hi*4+i; alpha lives at lane q)
    float a0 = __shfl(alpha, hi * 4 + 0, 64);
    float a1 = __shfl(alpha, hi * 4 + 1, 64);
    float a2 = __shfl(alpha, hi * 4 + 2, 64);
    float a3 = __shfl(alpha, hi * 4 + 3, 64);
#pragma unroll
    for (int e8 = 0; e8 < 8; ++e8) {
      acc[e8][0] *= a0; acc[e8][1] *= a1; acc[e8][2] *= a2; acc[e8][3] *= a3;
    }
    __syncthreads();  // P visible (and K reads done)

    // O += P * V : A = P rows (q=lo), B = V^T rows (e = e8*16+lo)
#pragma unroll
    for (int f2 = 0; f2 < 2; ++f2) {
      half8 pa = *reinterpret_cast<const half8*>(&Pw[lo * 72 + f2 * 32 + hi * 8]);
#pragma unroll
      for (int e8 = 0; e8 < 8; ++e8) {
        half8 bv = *reinterpret_cast<const half8*>(
            &VT_lds[(e8 * 16 + lo) * 72 + f2 * 32 + hi * 8]);
        acc[e8] = __builtin_amdgcn_mfma_f32_16x16x32_f16(pa, bv, acc[e8], 0, 0, 0);
      }
    }
  }

  float linv[4];
#pragma unroll
  for (int i = 0; i < 4; ++i) linv[i] = 1.0f / __shfl(l, hi * 4 + i, 64);
  const int orow = b * 4096 + qt * 64 + wv * 16;
#pragma unroll
  for (int e8 = 0; e8 < 8; ++e8)
#pragma unroll
    for (int i = 0; i < 4; ++i)
      out[(orow + hi * 4 + i) * 128 + e8 * 16 + lo] = acc[e8][i] * linv[i];
}

// ---------------------------------------------------------------------------
extern "C" void kernel_launch(void* const* d_in, const int* in_sizes, int n_in,
                              void* d_out, int out_size, void* d_ws, size_t ws_size,
                              hipStream_t stream) {
  const float* seq = (const float*)d_in[0];
  // d_in[1] = lengths: UNUSED by the reference (no masking).
  const float* Wq = (const float*)d_in[2];
  const float* Wk = (const float*)d_in[3];
  const float* Wv = (const float*)d_in[4];
  float* out = (float*)d_out;

  unsigned short* WT  = (unsigned short*)d_ws;   // 3*128*256
  unsigned short* Qb  = WT + 3 * 128 * 256;      // 16384*128
  unsigned short* Kb  = Qb + 16384 * 128;        // 16384*128
  unsigned short* VTb = Kb + 16384 * 128;        // 128*16384

  pack_w<<<384, 256, 0, stream>>>(Wq, Wk, Wv, WT);
  proj_kernel<<<256, 256, 0, stream>>>(seq, WT, Qb, Kb, VTb);
  attn_kernel<<<256, 256, 0, stream>>>(Qb, Kb, VTb, out);
}